// Round 5
// baseline (46.751 us; speedup 1.0000x reference)
//
#include <hip/hip_runtime.h>

#define NB 8
#define NC 4
#define NH 256
#define NW 256
#define HW (NH * NW)      // 65536
#define CHW (NC * HW)     // 262144
#define INFV 1e10f
#define MAIN_BLOCKS ((NB * HW) / 256)   // 2048
#define R0 4                             // batched window radius (exact cutoff 25)

// ---------------------------------------------------------------------------
// K1: EDT pass 1 along W — ballot version. One block (256 thr) per (b,h).
// Exact: d^2 with d<=255, INFV if class absent from row.
// ---------------------------------------------------------------------------
__global__ __launch_bounds__(256) void k_edt_w(const int* __restrict__ tgt,
                                               float* __restrict__ D) {
    int bh = blockIdx.x;            // b*NH + h
    int i  = threadIdx.x;
    int wv = i >> 6;                // wave id (0..3)
    int ln = i & 63;

    int tv = tgt[(size_t)bh * NW + i];

    __shared__ unsigned long long mk[NC][4];
    #pragma unroll
    for (int c = 0; c < NC; ++c) {
        unsigned long long m = __ballot(tv == c);
        if (ln == 0) mk[c][wv] = m;
    }
    __syncthreads();

    unsigned long long le = (ln == 63) ? ~0ull : ((1ull << (ln + 1)) - 1ull);
    unsigned long long ge = ~0ull << ln;

    float res[NC];
    #pragma unroll
    for (int c = 0; c < NC; ++c) {
        int jl = -1000;
        #pragma unroll
        for (int k = 0; k < 4; ++k) {
            unsigned long long x = mk[c][k];
            x = (k > wv) ? 0ull : ((k == wv) ? (x & le) : x);
            if (x) jl = k * 64 + 63 - __clzll((long long)x);
        }
        int jr = 1000;
        #pragma unroll
        for (int k = 3; k >= 0; --k) {
            unsigned long long x = mk[c][k];
            x = (k < wv) ? 0ull : ((k == wv) ? (x & ge) : x);
            if (x) jr = k * 64 + __ffsll((unsigned long long)x) - 1;
        }
        int dl = i - jl;
        int dr = jr - i;
        int dd = min(dl, dr);
        res[c] = (dd > 255) ? INFV : (float)(dd * dd);
    }

    int b = bh >> 8;
    int h = bh & 255;
    size_t o = (size_t)b * CHW + (size_t)h * NW + i;
    D[o]          = res[0];
    D[o + HW]     = res[1];
    D[o + 2 * HW] = res[2];
    D[o + 3 * HW] = res[3];
}

// ---------------------------------------------------------------------------
// softmax of the 4 channel logits at pixel offset hw of batch-base pred_b.
// ---------------------------------------------------------------------------
__device__ __forceinline__ void softmax4(const float* __restrict__ pred_b,
                                         int hw, float o[NC]) {
    float x0 = pred_b[hw];
    float x1 = pred_b[hw + HW];
    float x2 = pred_b[hw + 2 * HW];
    float x3 = pred_b[hw + 3 * HW];
    float m  = fmaxf(fmaxf(x0, x1), fmaxf(x2, x3));
    float e0 = __expf(x0 - m);
    float e1 = __expf(x1 - m);
    float e2 = __expf(x2 - m);
    float e3 = __expf(x3 - m);
    float inv = 1.0f / (e0 + e1 + e2 + e3);
    o[0] = e0 * inv; o[1] = e1 * inv; o[2] = e2 * inv; o[3] = e3 * inv;
}

// ---------------------------------------------------------------------------
// K2: fused kernel, one thread per (b,h,w).
//  - boundary |laplacian| of softmax (recomputed at 5 stencil pts — cheap)
//  - EDT pass-2: BATCHED +-R0-row window (36 independent coalesced loads,
//    one latency window, no dependent chain), exact cutoff at (R0+1)^2;
//    rare early-exit fallback scan for r > R0 (prob ~2e-9/px; also handles
//    the empty-channel case, which masks to 0 like the reference).
//  - block reduction -> partial[block]
// ---------------------------------------------------------------------------
__global__ __launch_bounds__(256) void k_main(const float* __restrict__ pred,
                                              const float* __restrict__ D,
                                              float2* __restrict__ partial) {
    int idx = blockIdx.x * 256 + threadIdx.x;   // over B*HW
    int b  = idx >> 16;
    int hw = idx & 65535;
    int h  = hw >> 8;
    int w  = hw & 255;

    const float* pred_b = pred + (size_t)b * CHW;

    // ---- issue the 36 window loads first (independent, coalesced) ----
    const float* fbase = D + (size_t)b * CHW + w;
    float win[NC][2 * R0 + 1];
    #pragma unroll
    for (int c = 0; c < NC; ++c) {
        #pragma unroll
        for (int dr = -R0; dr <= R0; ++dr) {
            int j = h + dr;
            win[c][dr + R0] = ((unsigned)j < NH)
                ? fbase[(size_t)c * HW + (j << 8)] : INFV;
        }
    }

    // ---- softmax at the 5 stencil points (zero pad outside image) ----
    float pc[NC], pu[NC] = {0,0,0,0}, pd[NC] = {0,0,0,0},
          pl[NC] = {0,0,0,0}, pr[NC] = {0,0,0,0};
    softmax4(pred_b, hw, pc);
    if (h > 0)   softmax4(pred_b, hw - NW, pu);
    if (h < 255) softmax4(pred_b, hw + NW, pd);
    if (w > 0)   softmax4(pred_b, hw - 1,  pl);
    if (w < 255) softmax4(pred_b, hw + 1,  pr);

    float num = 0.0f, den = 0.0f;
    #pragma unroll
    for (int c = 0; c < NC; ++c) {
        float lap = fabsf(pu[c] + pd[c] + pl[c] + pr[c] - 4.0f * pc[c]);

        // window min: dr^2 + win (all adds exact ints or INFV+small)
        float best = win[c][R0];
        #pragma unroll
        for (int r = 1; r <= R0; ++r) {
            float rr = (float)(r * r);
            best = fminf(best, rr + win[c][R0 - r]);
            best = fminf(best, rr + win[c][R0 + r]);
        }

        // fallback: exact early-exit scan for r > R0 (first iter breaks
        // immediately when best <= 25 — the overwhelmingly common case)
        const float* f = fbase + (size_t)c * HW;
        for (int r = R0 + 1; r < NH; ++r) {
            float rr = (float)(r * r);         // exact int <= 65025
            if (rr >= best) break;
            int hu = h - r, hd = h + r;
            if (hu >= 0) best = fminf(best, rr + f[hu << 8]);
            if (hd < NH) best = fminf(best, rr + f[hd << 8]);
        }

        float dv = (best > 1e8f) ? 0.0f : sqrtf(best);  // empty-channel mask

        num += lap * dv;
        den += lap;
    }

    #pragma unroll
    for (int off = 32; off > 0; off >>= 1) {
        num += __shfl_down(num, off);
        den += __shfl_down(den, off);
    }
    __shared__ float sn[4], sd[4];
    int lane = threadIdx.x & 63;
    int wvi  = threadIdx.x >> 6;
    if (lane == 0) { sn[wvi] = num; sd[wvi] = den; }
    __syncthreads();
    if (threadIdx.x == 0) {
        partial[blockIdx.x] = make_float2(sn[0] + sn[1] + sn[2] + sn[3],
                                          sd[0] + sd[1] + sd[2] + sd[3]);
    }
}

// ---------------------------------------------------------------------------
// K3: final reduction of partials + divide. One block.
// ---------------------------------------------------------------------------
__global__ __launch_bounds__(256) void k_final(const float2* __restrict__ partial,
                                               float* __restrict__ out) {
    double n = 0.0, d = 0.0;
    for (int i = threadIdx.x; i < MAIN_BLOCKS; i += 256) {
        float2 v = partial[i];
        n += (double)v.x;
        d += (double)v.y;
    }
    #pragma unroll
    for (int off = 32; off > 0; off >>= 1) {
        n += __shfl_down(n, off);
        d += __shfl_down(d, off);
    }
    __shared__ double snd[4], sdd[4];
    int lane = threadIdx.x & 63;
    int wv   = threadIdx.x >> 6;
    if (lane == 0) { snd[wv] = n; sdd[wv] = d; }
    __syncthreads();
    if (threadIdx.x == 0) {
        double nn = snd[0] + snd[1] + snd[2] + snd[3];
        double dd = sdd[0] + sdd[1] + sdd[2] + sdd[3];
        out[0] = (float)(nn / dd);
    }
}

extern "C" void kernel_launch(void* const* d_in, const int* in_sizes, int n_in,
                              void* d_out, int out_size, void* d_ws, size_t ws_size,
                              hipStream_t stream) {
    const float* pred = (const float*)d_in[0];
    const int*   tgt  = (const int*)d_in[1];
    float*       out  = (float*)d_out;

    float*  D       = (float*)d_ws;                     // 8 MB
    float2* partial = (float2*)(D + (size_t)NB * CHW);  // 16 KB

    k_edt_w<<<NB * NH,     256, 0, stream>>>(tgt, D);
    k_main <<<MAIN_BLOCKS, 256, 0, stream>>>(pred, D, partial);
    k_final<<<1,           256, 0, stream>>>(partial, out);
}

// Round 6
// 26.102 us; speedup vs baseline: 1.7911x; 1.7911x over previous
//
#include <hip/hip_runtime.h>

#define NB 8
#define NC 4
#define NH 256
#define NW 256
#define HW (NH * NW)      // 65536
#define CHW (NC * HW)     // 262144
#define INFV 1e10f
#define TH 4                              // output rows per block
#define MAIN_BLOCKS (NB * (NH / TH))      // 512
#define WR (TH + 8)                       // window rows held in registers (12)

// ---------------------------------------------------------------------------
// K1: EDT pass 1 along W — ballot version. One block (256 thr) per (b,h).
// Output: u16 squared distance (<= 65025, exact) or 65535 = class absent
// from this row (reference: 1e10).
// ---------------------------------------------------------------------------
__global__ __launch_bounds__(256) void k_edt_w(const int* __restrict__ tgt,
                                               unsigned short* __restrict__ D16) {
    int bh = blockIdx.x;            // b*NH + h
    int i  = threadIdx.x;
    int wv = i >> 6;                // wave id (0..3)
    int ln = i & 63;

    int tv = tgt[(size_t)bh * NW + i];

    __shared__ unsigned long long mk[NC][4];
    #pragma unroll
    for (int c = 0; c < NC; ++c) {
        unsigned long long m = __ballot(tv == c);
        if (ln == 0) mk[c][wv] = m;
    }
    __syncthreads();

    unsigned long long le = (ln == 63) ? ~0ull : ((1ull << (ln + 1)) - 1ull);
    unsigned long long ge = ~0ull << ln;

    unsigned short res[NC];
    #pragma unroll
    for (int c = 0; c < NC; ++c) {
        int jl = -1000;
        #pragma unroll
        for (int k = 0; k < 4; ++k) {
            unsigned long long x = mk[c][k];
            x = (k > wv) ? 0ull : ((k == wv) ? (x & le) : x);
            if (x) jl = k * 64 + 63 - __clzll((long long)x);
        }
        int jr = 1000;
        #pragma unroll
        for (int k = 3; k >= 0; --k) {
            unsigned long long x = mk[c][k];
            x = (k < wv) ? 0ull : ((k == wv) ? (x & ge) : x);
            if (x) jr = k * 64 + __ffsll((unsigned long long)x) - 1;
        }
        int dl = i - jl;
        int dr = jr - i;
        int dd = min(dl, dr);
        res[c] = (dd > 255) ? (unsigned short)65535
                            : (unsigned short)(dd * dd);
    }

    int b = bh >> 8;
    int h = bh & 255;
    size_t o = (size_t)b * CHW + (size_t)h * NW + i;
    D16[o]          = res[0];
    D16[o + HW]     = res[1];
    D16[o + 2 * HW] = res[2];
    D16[o + 3 * HW] = res[3];
}

// ---------------------------------------------------------------------------
// softmax of the 4 channel logits at pixel offset hw of batch-base pred_b.
// ---------------------------------------------------------------------------
__device__ __forceinline__ void softmax4(const float* __restrict__ pred_b,
                                         int hw, float o[NC]) {
    float x0 = pred_b[hw];
    float x1 = pred_b[hw + HW];
    float x2 = pred_b[hw + 2 * HW];
    float x3 = pred_b[hw + 3 * HW];
    float m  = fmaxf(fmaxf(x0, x1), fmaxf(x2, x3));
    float e0 = __expf(x0 - m);
    float e1 = __expf(x1 - m);
    float e2 = __expf(x2 - m);
    float e3 = __expf(x3 - m);
    float inv = 1.0f / (e0 + e1 + e2 + e3);
    o[0] = e0 * inv; o[1] = e1 * inv; o[2] = e2 * inv; o[3] = e3 * inv;
}

// ---------------------------------------------------------------------------
// K2: fused kernel. Block = 256 threads (w) x TH=4 output rows.
//  - window rows h0-4 .. h0+TH+3 (12) x 4ch loaded ONCE into registers
//    (coalesced u16; each value serves up to 9 outputs) — no dependent
//    load chain, 12 loads/px instead of 36.
//  - per-px window min over dr in [-4,4] from registers (exact cutoff 25);
//    rare exact fallback scan for best > 25 (also handles empty channel).
//  - boundary |laplacian| of softmax recomputed at 5 stencil pts.
//  - block reduction -> partial[block]
// ---------------------------------------------------------------------------
__global__ __launch_bounds__(256) void k_main(const float* __restrict__ pred,
                                              const unsigned short* __restrict__ D16,
                                              float2* __restrict__ partial) {
    int blk  = blockIdx.x;          // b*64 + tile
    int b    = blk >> 6;
    int tile = blk & 63;
    int h0   = tile * TH;
    int w    = threadIdx.x;

    const unsigned short* Db = D16 + (size_t)b * CHW + w;

    // ---- load the register window (fully unrolled -> static indices) ----
    float win[WR][NC];
    #pragma unroll
    for (int k = 0; k < WR; ++k) {
        int j = h0 - 4 + k;
        bool ok = (unsigned)j < (unsigned)NH;
        #pragma unroll
        for (int c = 0; c < NC; ++c) {
            unsigned short u = ok ? Db[(size_t)c * HW + (j << 8)]
                                  : (unsigned short)65535;
            win[k][c] = (u > 65025) ? INFV : (float)u;
        }
    }

    const float* pred_b = pred + (size_t)b * CHW;

    float num = 0.0f, den = 0.0f;
    #pragma unroll
    for (int r = 0; r < TH; ++r) {
        int h  = h0 + r;
        int hw = (h << 8) + w;

        float pc[NC], pu[NC] = {0,0,0,0}, pd[NC] = {0,0,0,0},
              pl[NC] = {0,0,0,0}, pr[NC] = {0,0,0,0};
        softmax4(pred_b, hw, pc);
        if (h > 0)   softmax4(pred_b, hw - NW, pu);
        if (h < 255) softmax4(pred_b, hw + NW, pd);
        if (w > 0)   softmax4(pred_b, hw - 1,  pl);
        if (w < 255) softmax4(pred_b, hw + 1,  pr);

        #pragma unroll
        for (int c = 0; c < NC; ++c) {
            float lap = fabsf(pu[c] + pd[c] + pl[c] + pr[c] - 4.0f * pc[c]);

            // window min from registers (all adds exact: ints <= 65041)
            float best = win[r + 4][c];
            #pragma unroll
            for (int dr = 1; dr <= 4; ++dr) {
                float rr = (float)(dr * dr);
                best = fminf(best, rr + win[r + 4 - dr][c]);
                best = fminf(best, rr + win[r + 4 + dr][c]);
            }

            // exact fallback for best > 25 (prob ~1e-10/px with this data;
            // also the empty/absent-channel path). Reads global u16.
            if (best > 25.0f) {
                const unsigned short* f = Db + (size_t)c * HW;
                for (int r2 = 5; r2 < NH; ++r2) {
                    float rr = (float)(r2 * r2);   // exact int <= 65025
                    if (rr >= best) break;
                    int hu = h - r2, hd = h + r2;
                    if (hu >= 0) {
                        unsigned short u = f[hu << 8];
                        if (u <= 65025) best = fminf(best, rr + (float)u);
                    }
                    if (hd < NH) {
                        unsigned short u = f[hd << 8];
                        if (u <= 65025) best = fminf(best, rr + (float)u);
                    }
                }
            }

            float dv = (best > 1e8f) ? 0.0f : sqrtf(best); // empty-ch mask
            num += lap * dv;
            den += lap;
        }
    }

    #pragma unroll
    for (int off = 32; off > 0; off >>= 1) {
        num += __shfl_down(num, off);
        den += __shfl_down(den, off);
    }
    __shared__ float sn[4], sd[4];
    int lane = threadIdx.x & 63;
    int wvi  = threadIdx.x >> 6;
    if (lane == 0) { sn[wvi] = num; sd[wvi] = den; }
    __syncthreads();
    if (threadIdx.x == 0) {
        partial[blockIdx.x] = make_float2(sn[0] + sn[1] + sn[2] + sn[3],
                                          sd[0] + sd[1] + sd[2] + sd[3]);
    }
}

// ---------------------------------------------------------------------------
// K3: final reduction of partials + divide. One block.
// ---------------------------------------------------------------------------
__global__ __launch_bounds__(256) void k_final(const float2* __restrict__ partial,
                                               float* __restrict__ out) {
    double n = 0.0, d = 0.0;
    for (int i = threadIdx.x; i < MAIN_BLOCKS; i += 256) {
        float2 v = partial[i];
        n += (double)v.x;
        d += (double)v.y;
    }
    #pragma unroll
    for (int off = 32; off > 0; off >>= 1) {
        n += __shfl_down(n, off);
        d += __shfl_down(d, off);
    }
    __shared__ double snd[4], sdd[4];
    int lane = threadIdx.x & 63;
    int wv   = threadIdx.x >> 6;
    if (lane == 0) { snd[wv] = n; sdd[wv] = d; }
    __syncthreads();
    if (threadIdx.x == 0) {
        double nn = snd[0] + snd[1] + snd[2] + snd[3];
        double dd = sdd[0] + sdd[1] + sdd[2] + sdd[3];
        out[0] = (float)(nn / dd);
    }
}

extern "C" void kernel_launch(void* const* d_in, const int* in_sizes, int n_in,
                              void* d_out, int out_size, void* d_ws, size_t ws_size,
                              hipStream_t stream) {
    const float* pred = (const float*)d_in[0];
    const int*   tgt  = (const int*)d_in[1];
    float*       out  = (float*)d_out;

    unsigned short* D16     = (unsigned short*)d_ws;                 // 4 MB
    float2*         partial = (float2*)((char*)d_ws + (size_t)NB * CHW * 2);

    k_edt_w<<<NB * NH,     256, 0, stream>>>(tgt, D16);
    k_main <<<MAIN_BLOCKS, 256, 0, stream>>>(pred, D16, partial);
    k_final<<<1,           256, 0, stream>>>(partial, out);
}